// Round 17
// baseline (84.595 us; speedup 1.0000x reference)
//
#include <hip/hip_runtime.h>

namespace {

constexpr int kBevH = 188, kBevW = 126, kP = kBevH * kBevW;   // 23688
constexpr int kB = 2, kN = 6, kC = 256, kHf = 48, kWf = 96;
constexpr int kHW = kHf * kWf;                                // 4608
constexpr int kPixBytes = kC * 2;                             // 512 B bf16
constexpr int kPTile = 32;
constexpr int kNTiles = (kP + kPTile - 1) / kPTile;           // 741
constexpr size_t kImgBytes = (size_t)kB * kN * kHW * kC * 2;  // 28.3 MB bf16
constexpr size_t kWsNeeded = kImgBytes;

typedef float vfloat4 __attribute__((ext_vector_type(4)));
typedef float vfloat2 __attribute__((ext_vector_type(2)));
typedef unsigned int vuint4 __attribute__((ext_vector_type(4)));

__device__ __forceinline__ unsigned short f2bf(float f) {     // RNE, finite
  union { float f; unsigned u; } a; a.f = f;
  unsigned r = a.u + 0x7fffu + ((a.u >> 16) & 1u);
  return (unsigned short)(r >> 16);
}
__device__ __forceinline__ float bfl(unsigned u) {
  union { unsigned u; float f; } a; a.u = u << 16; return a.f;
}
__device__ __forceinline__ float bfh(unsigned u) {
  union { unsigned u; float f; } a; a.u = u & 0xffff0000u; return a.f;
}

// ------------- K1: feats f32 [B,N,C,H,W] -> bf16 [B,N,HW,C] --------------
__global__ __launch_bounds__(256) void transpose_cvt_kernel(
    const float* __restrict__ src, unsigned short* __restrict__ dst) {
  __shared__ float tile[64][33];
  const int m = blockIdx.z;
  const int hw0 = blockIdx.x * 32;
  const int c0 = blockIdx.y * 64;
  const float* s = src + (size_t)m * kC * kHW;
  unsigned short* d = dst + (size_t)m * kHW * kC;
  const int hw = threadIdx.x & 31, cl = threadIdx.x >> 5;
#pragma unroll
  for (int k = 0; k < 8; ++k)
    tile[cl + 8 * k][hw] = s[(size_t)(c0 + cl + 8 * k) * kHW + hw0 + hw];
  __syncthreads();
  const int cp = threadIdx.x & 31, hwl = threadIdx.x >> 5;
#pragma unroll
  for (int k = 0; k < 4; ++k) {
    const int h = hwl + 8 * k;
    ushort2 uv;
    uv.x = f2bf(tile[2 * cp][h]);
    uv.y = f2bf(tile[2 * cp + 1][h]);
    *(ushort2*)(d + (size_t)(hw0 + h) * kC + c0 + 2 * cp) = uv;
  }
}

// ------------- K2: fused projection + paired-dwordx4 gather (R15) --------
// Change vs R15: the 12 image loads are NON-TEMPORAL (no L1 allocation).
// Theory: gather is L1 miss-path-bound (~15-20 B/cy/CU MSHR-limited);
// lines are reused across BLOCKS (L2), not within a wave -> L1 allocation
// buys nothing and costs eviction/alloc bandwidth.
__global__ __launch_bounds__(512) void gather_kernel(
    const unsigned char* __restrict__ tf, const float* __restrict__ intr,
    const float* __restrict__ c2c, float* __restrict__ out) {
  __shared__ float sm[kPTile][261];
  __shared__ int2 s_off[kPTile][kN];
  __shared__ vfloat2 s_wt2[kPTile][kN][2];   // [half] = {w_y0row, w_y1row}/6

  const int b = blockIdx.y;
  // bijective XCD swizzle (m204): contiguous tile chunk per XCD
  const int orig = blockIdx.x;
  constexpr int q = kNTiles / 8, r = kNTiles % 8;  // 92, 5
  const int xcd = orig & 7, idx = orig >> 3;
  const int tile = (xcd < r ? xcd * (q + 1) : r * (q + 1) + (xcd - r) * q) + idx;
  const int p0 = tile * kPTile;
  const int tid = threadIdx.x;

  // ---- phase 0: per-(p_local, cam) projection -> LDS records ----
  if (tid < kPTile * kN) {
    const int pl = tid / kN, n = tid - pl * kN;
    const int p = min(p0 + pl, kP - 1);
    const int pi = p / kBevW, pj = p - pi * kBevW;
    const float dxc = 75.2f / 188.0f, dyc = 50.4f / 126.0f;
    const float xcar = 0.5f * dxc + (float)pi * dxc;
    const float ycar = -25.2f + 0.5f * dyc + (float)pj * dyc;
    const float* M = c2c + ((size_t)b * kN + n) * 16;
    const float* K = intr + ((size_t)b * kN + n) * 9;
    float Xc = M[0] * xcar + M[1] * ycar + M[3];
    float Yc = M[4] * xcar + M[5] * ycar + M[7];
    float Zc = M[8] * xcar + M[9] * ycar + M[11];
    float u = K[0] * Xc + K[1] * Yc + K[2] * Zc;
    float v = K[3] * Xc + K[4] * Yc + K[5] * Zc;
    float w = K[6] * Xc + K[7] * Yc + K[8] * Zc;
    float z = fmaxf(w, 1e-4f);
    float uf = (u / z) * 0.125f;
    float vf = (v / z) * 0.125f;
    bool valid = (Zc > 0.1f) && (uf >= 0.0f) && (uf <= 95.0f) &&
                 (vf >= 0.0f) && (vf <= 47.0f);
    int2 ov = make_int2(0, 0);
    vfloat2 w0 = {0.f, 0.f}, w1 = {0.f, 0.f};
    if (valid) {
      // reproduce reference op order (norm round-trip)
      float un = (uf / 95.0f) * 2.0f - 1.0f;
      float vn = (vf / 47.0f) * 2.0f - 1.0f;
      float ix = (un + 1.0f) * 0.5f * 95.0f;
      float iy = (vn + 1.0f) * 0.5f * 47.0f;
      float x0f = floorf(ix), y0f = floorf(iy);
      float wx1 = ix - x0f, wx0 = 1.0f - wx1;
      float wy1 = iy - y0f, wy0 = 1.0f - wy1;
      int x0i = (int)x0f;              // in [0,95]
      int y0i = (int)y0f;              // in [0,47]
      int xb = min(x0i, 94);           // pair base column
      float h0 = (x0i <= 94) ? wx0 : 0.0f;
      float h1 = (x0i <= 94) ? wx1 : wx0;
      int y1i = min(y0i + 1, 47);      // wy1==0 when clamped (iy==47.0)
      const int pix = (b * kN + n) * kHW;
      ov.x = (pix + y0i * kWf + xb) * kPixBytes;
      ov.y = (pix + y1i * kWf + xb) * kPixBytes;
      const float s6 = 1.0f / 6.0f;    // fold mean over cams into weights
      w0 = (vfloat2){h0 * wy0 * s6, h0 * wy1 * s6};   // half 0 (x0 tap)
      w1 = (vfloat2){h1 * wy0 * s6, h1 * wy1 * s6};   // half 1 (x1 tap)
    }
    s_off[pl][n] = ov;
    s_wt2[pl][n][0] = w0;
    s_wt2[pl][n][1] = w1;
  }
  __syncthreads();

  const int w = tid >> 6, l = tid & 63;
  const int half = l >> 5;
  const int l16 = l << 4;            // byte offset within the 1KB pair
  const int cbase = ((l & 31) << 3) + (half << 2);

#pragma unroll
  for (int j = 0; j < 4; ++j) {
    const int pl = w * 4 + j;

    // LDS-broadcast records (<=2 unique addrs per wave -> free broadcast)
    const int2 o0 = s_off[pl][0], o1 = s_off[pl][1], o2 = s_off[pl][2],
               o3 = s_off[pl][3], o4 = s_off[pl][4], o5 = s_off[pl][5];
    const vfloat2 q0 = s_wt2[pl][0][half], q1 = s_wt2[pl][1][half],
                  q2 = s_wt2[pl][2][half], q3 = s_wt2[pl][3][half],
                  q4 = s_wt2[pl][4][half], q5 = s_wt2[pl][5][half];

    // ---- issue all 12 dwordx4 NON-TEMPORAL loads back-to-back ----
#define LD(nm, o) \
    const vuint4 nm##a = __builtin_nontemporal_load( \
        (const vuint4*)(tf + (size_t)o.x + l16)); \
    const vuint4 nm##b = __builtin_nontemporal_load( \
        (const vuint4*)(tf + (size_t)o.y + l16));
    LD(d0, o0) LD(d1, o1) LD(d2, o2) LD(d3, o3) LD(d4, o4) LD(d5, o5)
#undef LD

    vfloat2 ac0 = {0.f, 0.f}, ac1 = {0.f, 0.f},
            ac2 = {0.f, 0.f}, ac3 = {0.f, 0.f};
    // packed math: wv.x (y0-row weight) * da + wv.y (y1-row weight) * db,
    // two channels per v_pk_fma_f32
#define CAM(da, db, wv) { \
    const vfloat2 wA = {wv.x, wv.x}; \
    const vfloat2 wB = {wv.y, wv.y}; \
    ac0 += wA * (vfloat2){bfl(da.x), bfh(da.x)} \
         + wB * (vfloat2){bfl(db.x), bfh(db.x)}; \
    ac1 += wA * (vfloat2){bfl(da.y), bfh(da.y)} \
         + wB * (vfloat2){bfl(db.y), bfh(db.y)}; \
    ac2 += wA * (vfloat2){bfl(da.z), bfh(da.z)} \
         + wB * (vfloat2){bfl(db.z), bfh(db.z)}; \
    ac3 += wA * (vfloat2){bfl(da.w), bfh(da.w)} \
         + wB * (vfloat2){bfl(db.w), bfh(db.w)}; }
    CAM(d0a, d0b, q0) CAM(d1a, d1b, q1) CAM(d2a, d2b, q2)
    CAM(d3a, d3b, q3) CAM(d4a, d4b, q4) CAM(d5a, d5b, q5)
#undef CAM

    // sum the two x-halves (lane l <-> l+32)
    ac0.x += __shfl_xor(ac0.x, 32); ac0.y += __shfl_xor(ac0.y, 32);
    ac1.x += __shfl_xor(ac1.x, 32); ac1.y += __shfl_xor(ac1.y, 32);
    ac2.x += __shfl_xor(ac2.x, 32); ac2.y += __shfl_xor(ac2.y, 32);
    ac3.x += __shfl_xor(ac3.x, 32); ac3.y += __shfl_xor(ac3.y, 32);

    // lane handles channels 8*(l&31)..+7; half0 stores ch+0..3, half1 +4..7
    vfloat4 vs = half ? (vfloat4){ac2.x, ac2.y, ac3.x, ac3.y}
                      : (vfloat4){ac0.x, ac0.y, ac1.x, ac1.y};
    *(vfloat4*)&sm[pl][cbase] = vs;
  }
  __syncthreads();

  // write: 4 rounds; each round = 64 c-rows x 32 consecutive p (coalesced)
#pragma unroll
  for (int rd = 0; rd < 4; ++rd) {
    const int cr = rd * 64 + (tid >> 3);
    const int p4 = (tid & 7) * 4;
    const int pg = p0 + p4;
    if (pg < kP) {  // kP%4==0 -> whole float4 chunk valid
      vfloat4 v = {sm[p4][cr], sm[p4 + 1][cr], sm[p4 + 2][cr],
                   sm[p4 + 3][cr]};
      __builtin_nontemporal_store(
          v, (vfloat4*)(out + ((size_t)(b * kC + cr)) * kP + pg));
    }
  }
}

// ---------------- Fallback (R0 kernel) if ws too small -------------------
constexpr int kCChunk = 32;
__global__ __launch_bounds__(256) void ipm_project_kernel(
    const float* __restrict__ feats, const float* __restrict__ intr,
    const float* __restrict__ c2c, float* __restrict__ out) {
  const int p = blockIdx.x * 256 + threadIdx.x;
  const int b = blockIdx.y;
  const int c0 = blockIdx.z * kCChunk;
  const bool inrange = p < kP;
  const int pi = p / kBevW;
  const int pj = p - pi * kBevW;
  const float dx = 75.2f / 188.0f;
  const float dy = 50.4f / 126.0f;
  const float xcar = 0.5f * dx + (float)pi * dx;
  const float ycar = -25.2f + 0.5f * dy + (float)pj * dy;
  int tap[kN][4];
  float tw[kN][4];
  int vmask = 0;
  const float* Kb = intr + (size_t)b * kN * 9;
  const float* Mb = c2c + (size_t)b * kN * 16;
#pragma unroll
  for (int n = 0; n < kN; ++n) {
    const float* M = Mb + n * 16;
    const float* K = Kb + n * 9;
    float Xc = M[0] * xcar + M[1] * ycar + M[3];
    float Yc = M[4] * xcar + M[5] * ycar + M[7];
    float Zc = M[8] * xcar + M[9] * ycar + M[11];
    float u = K[0] * Xc + K[1] * Yc + K[2] * Zc;
    float v = K[3] * Xc + K[4] * Yc + K[5] * Zc;
    float w = K[6] * Xc + K[7] * Yc + K[8] * Zc;
    float z = fmaxf(w, 1e-4f);
    float uf = (u / z) * 0.125f;
    float vf = (v / z) * 0.125f;
    bool valid = inrange && (Zc > 0.1f) && (uf >= 0.0f) && (uf <= 95.0f) &&
                 (vf >= 0.0f) && (vf <= 47.0f);
    if (valid) {
      float un = (uf / 95.0f) * 2.0f - 1.0f;
      float vn = (vf / 47.0f) * 2.0f - 1.0f;
      float ix = (un + 1.0f) * 0.5f * 95.0f;
      float iy = (vn + 1.0f) * 0.5f * 47.0f;
      float x0f = floorf(ix), y0f = floorf(iy);
      float wx1 = ix - x0f, wx0 = 1.0f - wx1;
      float wy1 = iy - y0f, wy0 = 1.0f - wy1;
#pragma unroll
      for (int t = 0; t < 4; ++t) {
        float xf = x0f + (float)(t & 1);
        float yf = y0f + (float)(t >> 1);
        bool inb =
            (xf >= 0.0f) && (xf <= 95.0f) && (yf >= 0.0f) && (yf <= 47.0f);
        int xi = (int)fminf(fmaxf(xf, 0.0f), 95.0f);
        int yi = (int)fminf(fmaxf(yf, 0.0f), 47.0f);
        float wgt = ((t & 1) ? wx1 : wx0) * ((t >> 1) ? wy1 : wy0);
        tap[n][t] = yi * kWf + xi;
        tw[n][t] = inb ? wgt : 0.0f;
      }
      vmask |= (1 << n);
    }
  }
  const float inv_n = 1.0f / 6.0f;
#pragma unroll 4
  for (int k = 0; k < kCChunk; ++k) {
    const int c = c0 + k;
    float acc = 0.0f;
#pragma unroll
    for (int n = 0; n < kN; ++n) {
      if (vmask & (1 << n)) {
        const float* f = feats + ((size_t)(b * kN + n) * kC + c) * kHW;
        acc += f[tap[n][0]] * tw[n][0] + f[tap[n][1]] * tw[n][1] +
               f[tap[n][2]] * tw[n][2] + f[tap[n][3]] * tw[n][3];
      }
    }
    if (inrange) out[((size_t)b * kC + c) * kP + p] = acc * inv_n;
  }
}

}  // namespace

extern "C" void kernel_launch(void* const* d_in, const int* in_sizes, int n_in,
                              void* d_out, int out_size, void* d_ws,
                              size_t ws_size, hipStream_t stream) {
  const float* feats = (const float*)d_in[0];
  const float* intr = (const float*)d_in[1];
  const float* c2c = (const float*)d_in[2];
  float* out = (float*)d_out;

  if (ws_size >= kWsNeeded && d_ws != nullptr) {
    unsigned short* tf = (unsigned short*)d_ws;
    transpose_cvt_kernel<<<dim3(kHW / 32, kC / 64, kB * kN), 256, 0, stream>>>(
        feats, tf);
    gather_kernel<<<dim3(kNTiles, kB), 512, 0, stream>>>(
        (const unsigned char*)tf, intr, c2c, out);
  } else {
    dim3 grid((kP + 255) / 256, kB, kC / kCChunk);
    ipm_project_kernel<<<grid, dim3(256), 0, stream>>>(feats, intr, c2c, out);
  }
}

// Round 18
// 47.030 us; speedup vs baseline: 1.7987x; 1.7987x over previous
//
#include <hip/hip_runtime.h>

namespace {

constexpr int kBevH = 188, kBevW = 126, kP = kBevH * kBevW;   // 23688
constexpr int kB = 2, kN = 6, kC = 256, kHf = 48, kWf = 96;
constexpr int kHW = kHf * kWf;                                // 4608
constexpr int kPixBytes = kC * 2;                             // 512 B bf16
constexpr int kPTile = 32;
constexpr int kNTiles = (kP + kPTile - 1) / kPTile;           // 741
constexpr size_t kImgBytes = (size_t)kB * kN * kHW * kC * 2;  // 28.3 MB bf16
constexpr size_t kWsNeeded = kImgBytes;

typedef float vfloat4 __attribute__((ext_vector_type(4)));
typedef float vfloat2 __attribute__((ext_vector_type(2)));

__device__ __forceinline__ unsigned short f2bf(float f) {     // RNE, finite
  union { float f; unsigned u; } a; a.f = f;
  unsigned r = a.u + 0x7fffu + ((a.u >> 16) & 1u);
  return (unsigned short)(r >> 16);
}
__device__ __forceinline__ float bfl(unsigned u) {
  union { unsigned u; float f; } a; a.u = u << 16; return a.f;
}
__device__ __forceinline__ float bfh(unsigned u) {
  union { unsigned u; float f; } a; a.u = u & 0xffff0000u; return a.f;
}

// ------------- K1: feats f32 [B,N,C,H,W] -> bf16 [B,N,HW,C] --------------
__global__ __launch_bounds__(256) void transpose_cvt_kernel(
    const float* __restrict__ src, unsigned short* __restrict__ dst) {
  __shared__ float tile[64][33];
  const int m = blockIdx.z;
  const int hw0 = blockIdx.x * 32;
  const int c0 = blockIdx.y * 64;
  const float* s = src + (size_t)m * kC * kHW;
  unsigned short* d = dst + (size_t)m * kHW * kC;
  const int hw = threadIdx.x & 31, cl = threadIdx.x >> 5;
#pragma unroll
  for (int k = 0; k < 8; ++k)
    tile[cl + 8 * k][hw] = s[(size_t)(c0 + cl + 8 * k) * kHW + hw0 + hw];
  __syncthreads();
  const int cp = threadIdx.x & 31, hwl = threadIdx.x >> 5;
#pragma unroll
  for (int k = 0; k < 4; ++k) {
    const int h = hwl + 8 * k;
    ushort2 uv;
    uv.x = f2bf(tile[2 * cp][h]);
    uv.y = f2bf(tile[2 * cp + 1][h]);
    *(ushort2*)(d + (size_t)(hw0 + h) * kC + c0 + 2 * cp) = uv;
  }
}

// ------------- K2: fused projection + paired-dwordx4 gather (R15) --------
// Proven-best structure: 32 consecutive p per block, m204 chunked XCD
// swizzle (full-line L2 writes), packed f32x2 math, per-half weights in
// LDS, 1/6 folded into weights, normal (L1-allocating) loads — R17 proved
// ~half the gather loads are L1 hits; NT loads cost 2.5x.
__global__ __launch_bounds__(512) void gather_kernel(
    const unsigned char* __restrict__ tf, const float* __restrict__ intr,
    const float* __restrict__ c2c, float* __restrict__ out) {
  __shared__ float sm[kPTile][261];
  __shared__ int2 s_off[kPTile][kN];
  __shared__ vfloat2 s_wt2[kPTile][kN][2];   // [half] = {w_y0row, w_y1row}/6

  const int b = blockIdx.y;
  // bijective XCD swizzle (m204): contiguous tile chunk per XCD
  const int orig = blockIdx.x;
  constexpr int q = kNTiles / 8, r = kNTiles % 8;  // 92, 5
  const int xcd = orig & 7, idx = orig >> 3;
  const int tile = (xcd < r ? xcd * (q + 1) : r * (q + 1) + (xcd - r) * q) + idx;
  const int p0 = tile * kPTile;
  const int tid = threadIdx.x;

  // ---- phase 0: per-(p_local, cam) projection -> LDS records ----
  if (tid < kPTile * kN) {
    const int pl = tid / kN, n = tid - pl * kN;
    const int p = min(p0 + pl, kP - 1);
    const int pi = p / kBevW, pj = p - pi * kBevW;
    const float dxc = 75.2f / 188.0f, dyc = 50.4f / 126.0f;
    const float xcar = 0.5f * dxc + (float)pi * dxc;
    const float ycar = -25.2f + 0.5f * dyc + (float)pj * dyc;
    const float* M = c2c + ((size_t)b * kN + n) * 16;
    const float* K = intr + ((size_t)b * kN + n) * 9;
    float Xc = M[0] * xcar + M[1] * ycar + M[3];
    float Yc = M[4] * xcar + M[5] * ycar + M[7];
    float Zc = M[8] * xcar + M[9] * ycar + M[11];
    float u = K[0] * Xc + K[1] * Yc + K[2] * Zc;
    float v = K[3] * Xc + K[4] * Yc + K[5] * Zc;
    float w = K[6] * Xc + K[7] * Yc + K[8] * Zc;
    float z = fmaxf(w, 1e-4f);
    float uf = (u / z) * 0.125f;
    float vf = (v / z) * 0.125f;
    bool valid = (Zc > 0.1f) && (uf >= 0.0f) && (uf <= 95.0f) &&
                 (vf >= 0.0f) && (vf <= 47.0f);
    int2 ov = make_int2(0, 0);
    vfloat2 w0 = {0.f, 0.f}, w1 = {0.f, 0.f};
    if (valid) {
      // reproduce reference op order (norm round-trip)
      float un = (uf / 95.0f) * 2.0f - 1.0f;
      float vn = (vf / 47.0f) * 2.0f - 1.0f;
      float ix = (un + 1.0f) * 0.5f * 95.0f;
      float iy = (vn + 1.0f) * 0.5f * 47.0f;
      float x0f = floorf(ix), y0f = floorf(iy);
      float wx1 = ix - x0f, wx0 = 1.0f - wx1;
      float wy1 = iy - y0f, wy0 = 1.0f - wy1;
      int x0i = (int)x0f;              // in [0,95]
      int y0i = (int)y0f;              // in [0,47]
      int xb = min(x0i, 94);           // pair base column
      float h0 = (x0i <= 94) ? wx0 : 0.0f;
      float h1 = (x0i <= 94) ? wx1 : wx0;
      int y1i = min(y0i + 1, 47);      // wy1==0 when clamped (iy==47.0)
      const int pix = (b * kN + n) * kHW;
      ov.x = (pix + y0i * kWf + xb) * kPixBytes;
      ov.y = (pix + y1i * kWf + xb) * kPixBytes;
      const float s6 = 1.0f / 6.0f;    // fold mean over cams into weights
      w0 = (vfloat2){h0 * wy0 * s6, h0 * wy1 * s6};   // half 0 (x0 tap)
      w1 = (vfloat2){h1 * wy0 * s6, h1 * wy1 * s6};   // half 1 (x1 tap)
    }
    s_off[pl][n] = ov;
    s_wt2[pl][n][0] = w0;
    s_wt2[pl][n][1] = w1;
  }
  __syncthreads();

  const int w = tid >> 6, l = tid & 63;
  const int half = l >> 5;
  const int l16 = l << 4;            // byte offset within the 1KB pair
  const int cbase = ((l & 31) << 3) + (half << 2);

#pragma unroll
  for (int j = 0; j < 4; ++j) {
    const int pl = w * 4 + j;

    // LDS-broadcast records (<=2 unique addrs per wave -> free broadcast)
    const int2 o0 = s_off[pl][0], o1 = s_off[pl][1], o2 = s_off[pl][2],
               o3 = s_off[pl][3], o4 = s_off[pl][4], o5 = s_off[pl][5];
    const vfloat2 q0 = s_wt2[pl][0][half], q1 = s_wt2[pl][1][half],
                  q2 = s_wt2[pl][2][half], q3 = s_wt2[pl][3][half],
                  q4 = s_wt2[pl][4][half], q5 = s_wt2[pl][5][half];

    // ---- issue all 12 dwordx4 loads back-to-back ----
#define LD(nm, o) \
    const uint4 nm##a = *(const uint4*)(tf + (size_t)o.x + l16); \
    const uint4 nm##b = *(const uint4*)(tf + (size_t)o.y + l16);
    LD(d0, o0) LD(d1, o1) LD(d2, o2) LD(d3, o3) LD(d4, o4) LD(d5, o5)
#undef LD

    vfloat2 ac0 = {0.f, 0.f}, ac1 = {0.f, 0.f},
            ac2 = {0.f, 0.f}, ac3 = {0.f, 0.f};
    // packed math: wv.x (y0-row weight) * da + wv.y (y1-row weight) * db,
    // two channels per v_pk_fma_f32
#define CAM(da, db, wv) { \
    const vfloat2 wA = {wv.x, wv.x}; \
    const vfloat2 wB = {wv.y, wv.y}; \
    ac0 += wA * (vfloat2){bfl(da.x), bfh(da.x)} \
         + wB * (vfloat2){bfl(db.x), bfh(db.x)}; \
    ac1 += wA * (vfloat2){bfl(da.y), bfh(da.y)} \
         + wB * (vfloat2){bfl(db.y), bfh(db.y)}; \
    ac2 += wA * (vfloat2){bfl(da.z), bfh(da.z)} \
         + wB * (vfloat2){bfl(db.z), bfh(db.z)}; \
    ac3 += wA * (vfloat2){bfl(da.w), bfh(da.w)} \
         + wB * (vfloat2){bfl(db.w), bfh(db.w)}; }
    CAM(d0a, d0b, q0) CAM(d1a, d1b, q1) CAM(d2a, d2b, q2)
    CAM(d3a, d3b, q3) CAM(d4a, d4b, q4) CAM(d5a, d5b, q5)
#undef CAM

    // sum the two x-halves (lane l <-> l+32)
    ac0.x += __shfl_xor(ac0.x, 32); ac0.y += __shfl_xor(ac0.y, 32);
    ac1.x += __shfl_xor(ac1.x, 32); ac1.y += __shfl_xor(ac1.y, 32);
    ac2.x += __shfl_xor(ac2.x, 32); ac2.y += __shfl_xor(ac2.y, 32);
    ac3.x += __shfl_xor(ac3.x, 32); ac3.y += __shfl_xor(ac3.y, 32);

    // lane handles channels 8*(l&31)..+7; half0 stores ch+0..3, half1 +4..7
    vfloat4 vs = half ? (vfloat4){ac2.x, ac2.y, ac3.x, ac3.y}
                      : (vfloat4){ac0.x, ac0.y, ac1.x, ac1.y};
    *(vfloat4*)&sm[pl][cbase] = vs;
  }
  __syncthreads();

  // write: 4 rounds; each round = 64 c-rows x 32 consecutive p (coalesced)
#pragma unroll
  for (int rd = 0; rd < 4; ++rd) {
    const int cr = rd * 64 + (tid >> 3);
    const int p4 = (tid & 7) * 4;
    const int pg = p0 + p4;
    if (pg < kP) {  // kP%4==0 -> whole float4 chunk valid
      vfloat4 v = {sm[p4][cr], sm[p4 + 1][cr], sm[p4 + 2][cr],
                   sm[p4 + 3][cr]};
      __builtin_nontemporal_store(
          v, (vfloat4*)(out + ((size_t)(b * kC + cr)) * kP + pg));
    }
  }
}

// ---------------- Fallback (R0 kernel) if ws too small -------------------
constexpr int kCChunk = 32;
__global__ __launch_bounds__(256) void ipm_project_kernel(
    const float* __restrict__ feats, const float* __restrict__ intr,
    const float* __restrict__ c2c, float* __restrict__ out) {
  const int p = blockIdx.x * 256 + threadIdx.x;
  const int b = blockIdx.y;
  const int c0 = blockIdx.z * kCChunk;
  const bool inrange = p < kP;
  const int pi = p / kBevW;
  const int pj = p - pi * kBevW;
  const float dx = 75.2f / 188.0f;
  const float dy = 50.4f / 126.0f;
  const float xcar = 0.5f * dx + (float)pi * dx;
  const float ycar = -25.2f + 0.5f * dy + (float)pj * dy;
  int tap[kN][4];
  float tw[kN][4];
  int vmask = 0;
  const float* Kb = intr + (size_t)b * kN * 9;
  const float* Mb = c2c + (size_t)b * kN * 16;
#pragma unroll
  for (int n = 0; n < kN; ++n) {
    const float* M = Mb + n * 16;
    const float* K = Kb + n * 9;
    float Xc = M[0] * xcar + M[1] * ycar + M[3];
    float Yc = M[4] * xcar + M[5] * ycar + M[7];
    float Zc = M[8] * xcar + M[9] * ycar + M[11];
    float u = K[0] * Xc + K[1] * Yc + K[2] * Zc;
    float v = K[3] * Xc + K[4] * Yc + K[5] * Zc;
    float w = K[6] * Xc + K[7] * Yc + K[8] * Zc;
    float z = fmaxf(w, 1e-4f);
    float uf = (u / z) * 0.125f;
    float vf = (v / z) * 0.125f;
    bool valid = inrange && (Zc > 0.1f) && (uf >= 0.0f) && (uf <= 95.0f) &&
                 (vf >= 0.0f) && (vf <= 47.0f);
    if (valid) {
      float un = (uf / 95.0f) * 2.0f - 1.0f;
      float vn = (vf / 47.0f) * 2.0f - 1.0f;
      float ix = (un + 1.0f) * 0.5f * 95.0f;
      float iy = (vn + 1.0f) * 0.5f * 47.0f;
      float x0f = floorf(ix), y0f = floorf(iy);
      float wx1 = ix - x0f, wx0 = 1.0f - wx1;
      float wy1 = iy - y0f, wy0 = 1.0f - wy1;
#pragma unroll
      for (int t = 0; t < 4; ++t) {
        float xf = x0f + (float)(t & 1);
        float yf = y0f + (float)(t >> 1);
        bool inb =
            (xf >= 0.0f) && (xf <= 95.0f) && (yf >= 0.0f) && (yf <= 47.0f);
        int xi = (int)fminf(fmaxf(xf, 0.0f), 95.0f);
        int yi = (int)fminf(fmaxf(yf, 0.0f), 47.0f);
        float wgt = ((t & 1) ? wx1 : wx0) * ((t >> 1) ? wy1 : wy0);
        tap[n][t] = yi * kWf + xi;
        tw[n][t] = inb ? wgt : 0.0f;
      }
      vmask |= (1 << n);
    }
  }
  const float inv_n = 1.0f / 6.0f;
#pragma unroll 4
  for (int k = 0; k < kCChunk; ++k) {
    const int c = c0 + k;
    float acc = 0.0f;
#pragma unroll
    for (int n = 0; n < kN; ++n) {
      if (vmask & (1 << n)) {
        const float* f = feats + ((size_t)(b * kN + n) * kC + c) * kHW;
        acc += f[tap[n][0]] * tw[n][0] + f[tap[n][1]] * tw[n][1] +
               f[tap[n][2]] * tw[n][2] + f[tap[n][3]] * tw[n][3];
      }
    }
    if (inrange) out[((size_t)b * kC + c) * kP + p] = acc * inv_n;
  }
}

}  // namespace

extern "C" void kernel_launch(void* const* d_in, const int* in_sizes, int n_in,
                              void* d_out, int out_size, void* d_ws,
                              size_t ws_size, hipStream_t stream) {
  const float* feats = (const float*)d_in[0];
  const float* intr = (const float*)d_in[1];
  const float* c2c = (const float*)d_in[2];
  float* out = (float*)d_out;

  if (ws_size >= kWsNeeded && d_ws != nullptr) {
    unsigned short* tf = (unsigned short*)d_ws;
    transpose_cvt_kernel<<<dim3(kHW / 32, kC / 64, kB * kN), 256, 0, stream>>>(
        feats, tf);
    gather_kernel<<<dim3(kNTiles, kB), 512, 0, stream>>>(
        (const unsigned char*)tf, intr, c2c, out);
  } else {
    dim3 grid((kP + 255) / 256, kB, kC / kCChunk);
    ipm_project_kernel<<<grid, dim3(256), 0, stream>>>(feats, intr, c2c, out);
  }
}